// Round 11
// baseline (6397.710 us; speedup 1.0000x reference)
//
#include <hip/hip_runtime.h>

// ---------------------------------------------------------------------------
// TrueMambaBlock on MI355X — fp32 pipeline v4: occupancy-targeted k_fused.
// (resubmitted unchanged; audited 3x; awaiting first bench since v3 PASSED)
// vs v3 (PASSED, 1977us, k_fused=2x927us @ 24% occupancy, VALU 40%, HBM 1%):
//   - x-window LDS buffer removed (conv via rolling regs from global)
//   - 32-token half-chunks: LDS 65088 -> 41024 B (3 blocks/CU by LDS)
//   - __launch_bounds__(512,6): VGPR <= 85 -> 24 waves/CU (was ~8)
//   - softplus via __logf(1+__expf) instead of libm log1pf
// B=1, C=64, H=W=256, D_INNER=128, D_STATE=16, D_CONV=4, DT_RANK=4
// ---------------------------------------------------------------------------

// ---- ws layout (float offsets) ---------------------------------------------
static constexpr size_t OFF_YN   = 0;                    // 65536*64 normalized tokens [tok][c]
static constexpr size_t OFF_XZ   = OFF_YN + 4194304;     // 65536*256 xz (per orientation, reused)
static constexpr size_t OFF_ACCD = OFF_XZ + 16777216;    // 4 * 65536*64 outproj partials (+red alias)
static constexpr size_t WS_FLOATS = OFF_ACCD + 16777216; // 37,748,736 floats = 144 MiB

__device__ __forceinline__ float silu_f(float v) { return v / (1.f + __expf(-v)); }

// ---- zero the reduction accumulator ---------------------------------------
__global__ void k_zero(float* r) {
    if (threadIdx.x < 2) r[threadIdx.x] = 0.f;
}

// ---- global mean / meansq reduction over 4,194,304 floats ------------------
__global__ __launch_bounds__(256) void k_reduce(const float* __restrict__ x, float* __restrict__ red) {
    int tid = blockIdx.x * 256 + threadIdx.x;           // 262144 threads
    const float4* x4 = (const float4*)x;
    float s = 0.f, sq = 0.f;
    #pragma unroll
    for (int i = 0; i < 4; i++) {
        float4 v = x4[tid + i * 262144];
        s  += v.x + v.y + v.z + v.w;
        sq += v.x * v.x + v.y * v.y + v.z * v.z + v.w * v.w;
    }
    #pragma unroll
    for (int off = 32; off; off >>= 1) {
        s  += __shfl_down(s, off);
        sq += __shfl_down(sq, off);
    }
    __shared__ float ls[8], lq[8];
    int wid = threadIdx.x >> 6, lane = threadIdx.x & 63;
    if (lane == 0) { ls[wid] = s; lq[wid] = sq; }
    __syncthreads();
    if (threadIdx.x == 0) {
        float ts = 0.f, tq = 0.f;
        for (int w = 0; w < 4; w++) { ts += ls[w]; tq += lq[w]; }
        atomicAdd(&red[0], ts);
        atomicAdd(&red[1], tq);
    }
}

// ---- normalize + transpose [c][hw] -> [tok][c] -----------------------------
__global__ __launch_bounds__(256) void k_norm(const float* __restrict__ x, const float* __restrict__ red,
                                              const float* __restrict__ gw, const float* __restrict__ gb,
                                              float* __restrict__ yn) {
    __shared__ float tile[64][65];
    int hw0 = blockIdx.x * 64;
    float mean = red[0] * (1.f / 4194304.f);
    float var  = red[1] * (1.f / 4194304.f) - mean * mean;
    float rstd = rsqrtf(var + 1e-5f);
    int tx = threadIdx.x & 63, ty = threadIdx.x >> 6;
    #pragma unroll
    for (int i = 0; i < 16; i++) {
        int c = i * 4 + ty;
        tile[c][tx] = x[c * 65536 + hw0 + tx];
    }
    __syncthreads();
    int c = tx;
    float sc = gw[c] * rstd;
    float bb = gb[c] - mean * sc;
    #pragma unroll
    for (int i = 0; i < 16; i++) {
        int m = i * 4 + ty;
        yn[(size_t)(hw0 + m) * 64 + c] = tile[c][m] * sc + bb;
    }
}

// ---- xz GEMM: xz[tok][256] = yn_token @ in_w.T ------------------------------
// grid 2048: bid>>1 = 64-token tile, bid&1 = 128-wide N chunk.
// orient 0: token t -> yn row t; orient 1 (col): t=(s,p) -> yn row p*256+s
__global__ __launch_bounds__(256) void k_xz(const float* __restrict__ yn, const float* __restrict__ in_w,
                                            float* __restrict__ xz, int orient) {
    __shared__ __align__(16) float tk[64][68];    // [k][m]
    __shared__ __align__(16) float wl[64][132];   // [k][n]
    int mt = blockIdx.x >> 1, nc = blockIdx.x & 1;
    int t0 = mt * 64;
    int tid = threadIdx.x;
    {   // stage tokens, transposed to k-major
        int k = tid & 63, mg = tid >> 6;
        for (int ms = 0; ms < 64; ms += 4) {
            int m = ms + mg;
            int t = t0 + m;
            size_t addr;
            if (orient == 0) addr = (size_t)t * 64 + k;
            else { int s = t >> 8, p = t & 255; addr = (size_t)(p * 256 + s) * 64 + k; }
            tk[k][m] = yn[addr];
        }
    }
    {   // stage weights chunk (128 n), transposed to k-major
        int k = tid & 63, ng = tid >> 6;
        for (int i = 0; i < 32; i++) {
            int n = i * 4 + ng;
            wl[k][n] = in_w[(size_t)(nc * 128 + n) * 64 + k];
        }
    }
    __syncthreads();
    int m0 = (tid & 15) * 4, n0 = (tid >> 4) * 8;
    float acc[4][8];
    #pragma unroll
    for (int i = 0; i < 4; i++)
        #pragma unroll
        for (int j = 0; j < 8; j++) acc[i][j] = 0.f;
    #pragma unroll 4
    for (int k = 0; k < 64; k++) {
        float4 tv = *(const float4*)&tk[k][m0];
        float tvf[4] = { tv.x, tv.y, tv.z, tv.w };
        #pragma unroll
        for (int i4 = 0; i4 < 2; i4++) {
            float4 wv = *(const float4*)&wl[k][n0 + i4 * 4];
            float wvf[4] = { wv.x, wv.y, wv.z, wv.w };
            #pragma unroll
            for (int m = 0; m < 4; m++)
                #pragma unroll
                for (int j = 0; j < 4; j++)
                    acc[m][i4 * 4 + j] += tvf[m] * wvf[j];
        }
    }
    #pragma unroll
    for (int m = 0; m < 4; m++) {
        size_t t = t0 + m0 + m;
        #pragma unroll
        for (int i4 = 0; i4 < 2; i4++) {
            float4 v = { acc[m][i4 * 4 + 0], acc[m][i4 * 4 + 1], acc[m][i4 * 4 + 2], acc[m][i4 * 4 + 3] };
            *(float4*)&xz[t * 256 + nc * 128 + n0 + i4 * 4] = v;
        }
    }
}

// ---- fused conv4+silu + xproj + dt + scan + gating + outproj ----------------
// grid (256, 2): bid.x = seq s, bid.y = dir. 512 threads, 8 half-chunks of 32
// tokens (fwd: hc 0..7, bwd: hc 7..0). Per half-chunk:
//   conv+silu via rolling regs from global xz -> xcl [32][132]
//   -> xproj x_dbl [32][40] -> 32-step scan (dt+exp inline; q==0 writes
//   ycore=y+D*x over consumed xcl slot) -> gating in-place -> outproj GEMM
//   -> accD partial write.
// LDS 41024 B, launch_bounds(512,6) (VGPR<=85) -> 3 blocks/CU = 24 waves/CU.
__global__ __launch_bounds__(512, 6) void k_fused(const float* __restrict__ xz,
                                               const float* __restrict__ conv_w, const float* __restrict__ conv_b,
                                               const float* __restrict__ xproj_w,
                                               const float* __restrict__ dt_w, const float* __restrict__ dt_b,
                                               const float* __restrict__ A_log, const float* __restrict__ Dw,
                                               const float* __restrict__ out_w,
                                               float* __restrict__ accD) {
    __shared__ __align__(16) float sm[10256];
    float* xcl = sm;                      // [32][132] conv out / ycore / gated
    float* wp  = sm + 4224;               // [36][132] xproj weights
    float* xd  = sm + 4224 + 4752;        // [32][40] x_dbl
    const int tid = threadIdx.x;
    const int s = blockIdx.x, dir = blockIdx.y;
    const int seqbase = s * 256;

    // stage xproj weights once (36*128 = 4608 = 9*512)
    #pragma unroll
    for (int i = 0; i < 9; i++) {
        int lin = i * 512 + tid;
        wp[(lin >> 7) * 132 + (lin & 127)] = xproj_w[lin];
    }

    // per-thread constants
    const int d  = tid >> 2, q = tid & 3, q4 = q * 4;   // scan mapping
    const int dg = tid & 127;                            // conv/gating channel
    const int mg = tid >> 7;                             // 0..3 token group
    const float4 cw  = ((const float4*)conv_w)[dg];
    const float  cb  = conv_b[dg];
    const float4 dwv = ((const float4*)dt_w)[d];
    const float  dbv = dt_b[d];
    const float A0 = -__expf(A_log[d * 16 + q4 + 0]);
    const float A1 = -__expf(A_log[d * 16 + q4 + 1]);
    const float A2 = -__expf(A_log[d * 16 + q4 + 2]);
    const float A3 = -__expf(A_log[d * 16 + q4 + 3]);
    const float Dv = Dw[d];
    // conv tap weights: dir0: y[m]=cw.x*x[m-3]+cw.y*x[m-2]+cw.z*x[m-1]+cw.w*x[m]
    //                   dir1: y[m]=cw.w*x[m]+cw.z*x[m+1]+cw.y*x[m+2]+cw.x*x[m+3]
    const float w0 = dir ? cw.w : cw.x, w1 = dir ? cw.z : cw.y;
    const float w2 = dir ? cw.y : cw.z, w3 = dir ? cw.x : cw.w;
    float* ap = accD + (size_t)dir * 4194304 + (size_t)seqbase * 64;

    float h0 = 0.f, h1 = 0.f, h2 = 0.f, h3 = 0.f;

    for (int hci = 0; hci < 8; hci++) {
        const int hc = dir ? 7 - hci : hci;
        const int p0 = hc * 32;
        __syncthreads();   // prev outproj reads / wp-stage complete
        // conv + silu: thread (dg, mg) handles tokens lm = mg*8..mg*8+7
        {
            const int lbase = p0 + mg * 8 + (dir ? 0 : -3);  // local window start
            float a[11];
            #pragma unroll
            for (int j = 0; j < 11; j++) {
                int lp = lbase + j;
                a[j] = (lp >= 0 && lp < 256) ? xz[(size_t)(seqbase + lp) * 256 + dg] : 0.f;
            }
            #pragma unroll
            for (int j = 0; j < 8; j++) {
                float v = w0 * a[j] + w1 * a[j + 1] + w2 * a[j + 2] + w3 * a[j + 3] + cb;
                xcl[(mg * 8 + j) * 132 + dg] = silu_f(v);
            }
        }
        __syncthreads();
        // xproj: lm = tid>>4 (0..31), g = tid&15; outputs n = g, g+16, (g<4: g+32)
        {
            const int lm = tid >> 4, g = tid & 15;
            float ac0 = 0.f, ac1 = 0.f, ac2 = 0.f;
            for (int k4 = 0; k4 < 32; k4++) {
                float4 xv = *(const float4*)&xcl[lm * 132 + k4 * 4];
                float4 wa = *(const float4*)&wp[g * 132 + k4 * 4];
                float4 wb = *(const float4*)&wp[(g + 16) * 132 + k4 * 4];
                ac0 += xv.x * wa.x + xv.y * wa.y + xv.z * wa.z + xv.w * wa.w;
                ac1 += xv.x * wb.x + xv.y * wb.y + xv.z * wb.z + xv.w * wb.w;
                if (g < 4) {
                    float4 wc = *(const float4*)&wp[(g + 32) * 132 + k4 * 4];
                    ac2 += xv.x * wc.x + xv.y * wc.y + xv.z * wc.z + xv.w * wc.w;
                }
            }
            xd[lm * 40 + g]      = ac0;
            xd[lm * 40 + 16 + g] = ac1;
            if (g < 4) xd[lm * 40 + 32 + g] = ac2;
        }
        __syncthreads();
        // scan: 32 steps (bwd reversed); dt/exp inline
        {
            int t = dir ? 31 : 0;
            const int tstep = dir ? -1 : 1;
            for (int step = 0; step < 32; step++) {
                float4 r = *(const float4*)&xd[t * 40];
                float dtv = dbv + r.x * dwv.x + r.y * dwv.y + r.z * dwv.z + r.w * dwv.w;
                dtv = (dtv > 20.f) ? dtv : __logf(1.f + __expf(dtv));
                float xv = xcl[t * 132 + d];
                float4 B4 = *(const float4*)&xd[t * 40 + 4 + q4];
                float4 C4 = *(const float4*)&xd[t * 40 + 20 + q4];
                float e0 = __expf(dtv * A0), e1 = __expf(dtv * A1);
                float e2 = __expf(dtv * A2), e3 = __expf(dtv * A3);
                float dx = dtv * xv;
                h0 = e0 * h0 + dx * B4.x;
                h1 = e1 * h1 + dx * B4.y;
                h2 = e2 * h2 + dx * B4.z;
                h3 = e3 * h3 + dx * B4.w;
                float y = h0 * C4.x + h1 * C4.y + h2 * C4.z + h3 * C4.w;
                y += __shfl_xor(y, 1);
                y += __shfl_xor(y, 2);
                if (q == 0) xcl[t * 132 + d] = y + xv * Dv;   // ycore over consumed slot
                t += tstep;
            }
        }
        __syncthreads();
        // gating in-place: xcl[lm][dg] = ycore * silu(z)
        #pragma unroll
        for (int j = 0; j < 8; j++) {
            int lm = mg * 8 + j;
            float yc = xcl[lm * 132 + dg];
            float zv = xz[(size_t)(seqbase + p0 + lm) * 256 + 128 + dg];
            xcl[lm * 132 + dg] = yc * silu_f(zv);
        }
        __syncthreads();
        // outproj: rep = tid>>8 (n-half), m = (tid>>3)&31, n0 = rep*32+(tid&7)*4
        {
            const int rep = tid >> 8, m = (tid >> 3) & 31;
            const int n0 = rep * 32 + (tid & 7) * 4;
            float a0 = 0.f, a1 = 0.f, a2 = 0.f, a3 = 0.f;
            for (int k4 = 0; k4 < 32; k4++) {
                float4 xv = *(const float4*)&xcl[m * 132 + k4 * 4];
                float4 v0 = *(const float4*)&out_w[(n0 + 0) * 128 + k4 * 4];
                float4 v1 = *(const float4*)&out_w[(n0 + 1) * 128 + k4 * 4];
                float4 v2 = *(const float4*)&out_w[(n0 + 2) * 128 + k4 * 4];
                float4 v3 = *(const float4*)&out_w[(n0 + 3) * 128 + k4 * 4];
                a0 += xv.x * v0.x + xv.y * v0.y + xv.z * v0.z + xv.w * v0.w;
                a1 += xv.x * v1.x + xv.y * v1.y + xv.z * v1.z + xv.w * v1.w;
                a2 += xv.x * v2.x + xv.y * v2.y + xv.z * v2.z + xv.w * v2.w;
                a3 += xv.x * v3.x + xv.y * v3.y + xv.z * v3.z + xv.w * v3.w;
            }
            float4 v = { a0, a1, a2, a3 };
            *(float4*)&ap[(size_t)(p0 + m) * 64 + n0] = v;
        }
    }
}

// ---- final: out = x + proj_w @ (0.25 * (Rf + Rb + Cf^T + Cb^T)) -------------
__global__ __launch_bounds__(256) void k_final(const float* __restrict__ accD,
                                               const float* __restrict__ pw, const float* __restrict__ x,
                                               float* __restrict__ out) {
    __shared__ __align__(16) float tk[64][68];
    __shared__ __align__(16) float wl[64][68];
    int t0 = blockIdx.x * 64, tid = threadIdx.x;
    int hh = t0 >> 8, w0 = t0 & 255;
    for (int i = 0; i < 16; i++) {
        int m = i * 4 + (tid >> 6), k = tid & 63;
        size_t rt = (size_t)(t0 + m) * 64 + k;
        size_t ct = (size_t)((w0 + m) * 256 + hh) * 64 + k;
        tk[k][m] = 0.25f * (accD[rt] + accD[4194304 + rt] +
                            accD[8388608 + ct] + accD[12582912 + ct]);
    }
    for (int i = 0; i < 16; i++) {
        int n = i * 4 + (tid >> 6), k = tid & 63;
        wl[k][n] = pw[n * 64 + k];
    }
    __syncthreads();
    int m0 = (tid & 15) * 4, n0 = (tid >> 4) * 4;
    float a4[4][4];
    #pragma unroll
    for (int i = 0; i < 4; i++)
        #pragma unroll
        for (int j = 0; j < 4; j++) a4[i][j] = 0.f;
    #pragma unroll 4
    for (int k = 0; k < 64; k++) {
        float4 tv = *(const float4*)&tk[k][m0];
        float4 wv = *(const float4*)&wl[k][n0];
        float tvf[4] = { tv.x, tv.y, tv.z, tv.w };
        float wvf[4] = { wv.x, wv.y, wv.z, wv.w };
        #pragma unroll
        for (int m = 0; m < 4; m++)
            #pragma unroll
            for (int j = 0; j < 4; j++)
                a4[m][j] += tvf[m] * wvf[j];
    }
    #pragma unroll
    for (int j = 0; j < 4; j++) {
        int n = n0 + j;
        float4 r = *(const float4*)&x[(size_t)n * 65536 + t0 + m0];
        float4 v = { a4[0][j] + r.x, a4[1][j] + r.y, a4[2][j] + r.z, a4[3][j] + r.w };
        *(float4*)&out[(size_t)n * 65536 + t0 + m0] = v;
    }
}

// ---------------------------------------------------------------------------
extern "C" void kernel_launch(void* const* d_in, const int* in_sizes, int n_in,
                              void* d_out, int out_size, void* d_ws, size_t ws_size,
                              hipStream_t stream) {
    (void)n_in; (void)out_size;
    if (ws_size < WS_FLOATS * sizeof(float)) return;  // refuse rather than corrupt

    float* ws = (float*)d_ws;
    const float* x    = (const float*)d_in[0];
    const float* gn_w = (const float*)d_in[1];
    const float* gn_b = (const float*)d_in[2];

    // Input ordering: setup_inputs() dict order puts proj_w at index 3,
    // row params at 4..12, col at 13..21. Detect reference-arg order as fallback.
    int rbase, cbase;
    const float* proj_w;
    if (in_sizes[3] == 64 * 64) { proj_w = (const float*)d_in[3]; rbase = 4; cbase = 13; }
    else                        { rbase = 3; cbase = 12; proj_w = (const float*)d_in[21]; }

    float* yn   = ws + OFF_YN;
    float* xzb  = ws + OFF_XZ;
    float* accD = ws + OFF_ACCD;  // [4][65536][64]: Rf, Rb, Cf, Cb
    float* red  = ws + OFF_ACCD;  // alias: red live k_zero..k_norm only

    k_zero<<<1, 64, 0, stream>>>(red);
    k_reduce<<<1024, 256, 0, stream>>>(x, red);
    k_norm<<<1024, 256, 0, stream>>>(x, red, gn_w, gn_b, yn);

    for (int o = 0; o < 2; o++) {
        int base = (o == 0) ? rbase : cbase;
        const float* in_w    = (const float*)d_in[base + 0];
        const float* conv_w  = (const float*)d_in[base + 1];
        const float* conv_b  = (const float*)d_in[base + 2];
        const float* xproj_w = (const float*)d_in[base + 3];
        const float* dt_w    = (const float*)d_in[base + 4];
        const float* dt_b    = (const float*)d_in[base + 5];
        const float* A_log   = (const float*)d_in[base + 6];
        const float* Dp      = (const float*)d_in[base + 7];
        const float* out_w   = (const float*)d_in[base + 8];

        k_xz<<<2048, 256, 0, stream>>>(yn, in_w, xzb, o);
        k_fused<<<dim3(256, 2), 512, 0, stream>>>(xzb, conv_w, conv_b, xproj_w,
                                                  dt_w, dt_b, A_log, Dp, out_w,
                                                  accD + (size_t)o * 8388608);
    }

    k_final<<<1024, 256, 0, stream>>>(accD, proj_w, x, (float*)d_out);
}